// Round 12
// baseline (238.116 us; speedup 1.0000x reference)
//
#include <hip/hip_runtime.h>
#include <stdint.h>

#define NS   512      // batch size
#define DDIM 256      // feature dim
#define LL   8000     // labels
#define CC   8        // cameras
#define PP   64000    // proxies = LL*CC
#define KTOP 50
#define CAP  1024     // candidate buffer capacity per row
#define BM   128      // rows per block
#define BN   128      // cols per block
#define NCT  (PP/BN)  // 500 col-tiles
#define K2C  28.853900817779268f   // log2(e)/T, T=0.05

typedef float f32x4 __attribute__((ext_vector_type(4)));
typedef short bf16x8 __attribute__((ext_vector_type(8)));

__device__ __forceinline__ ushort f2bf(float x) {
    uint32_t b = __float_as_uint(x);
    b += 0x7fffu + ((b >> 16) & 1u);   // round-to-nearest-even
    return (ushort)(b >> 16);
}
__device__ __forceinline__ float bf2f(ushort u) {
    return __uint_as_float(((uint32_t)u) << 16);
}

// ---------------------------------------------------------------------------
// Kernel 1: normalize feats rows -> bf16; gather labels/cams; zero gcount.
__global__ void k_norm_gather(const float* __restrict__ feats,
                              const int* __restrict__ indexes,
                              const int* __restrict__ ltab,
                              const int* __restrict__ ctab,
                              ushort* __restrict__ feats_b,
                              int* __restrict__ labels,
                              int* __restrict__ cams,
                              int* __restrict__ gcount) {
    const int n = blockIdx.x;
    const int lane = threadIdx.x;  // 0..63
    f32x4 v = ((const f32x4*)(feats + (size_t)n * DDIM))[lane];
    float ss = v[0]*v[0] + v[1]*v[1] + v[2]*v[2] + v[3]*v[3];
#pragma unroll
    for (int off = 32; off > 0; off >>= 1) ss += __shfl_down(ss, off);
    float tot = __shfl(ss, 0);
    float sc = 1.0f / sqrtf(tot);
    ushort4 o;
    o.x = f2bf(v[0] * sc); o.y = f2bf(v[1] * sc);
    o.z = f2bf(v[2] * sc); o.w = f2bf(v[3] * sc);
    ((ushort4*)(feats_b + (size_t)n * DDIM))[lane] = o;
    if (lane == 0) {
        int idx = indexes[n];
        labels[n] = ltab[idx];
        cams[n] = ctab[idx];
        gcount[n] = 0;
    }
}

// ---------------------------------------------------------------------------
// Kernel 2: fused GEMM (m93 structure: both operands LDS-fed) + epilogue.
// Block (ct, rt): rows [rt*128,+128) x cols [ct*128,+128).
// A-tile staged once (bf16, padded [128][264]); B staged per K-step
// ([128][36] bf16, converted from f32 in-flight, read exactly once from HBM).
// 4 waves (2x2), wave-tile 64x64, acc[4][4] f32x4 = 64 f32 (AGPR).
__global__ __launch_bounds__(256, 2)
void k_gemm_fused(const ushort* __restrict__ A, const float* __restrict__ B,
                  const int* __restrict__ labels, const int* __restrict__ cams,
                  float* __restrict__ partial, float* __restrict__ cand,
                  int* __restrict__ gcount, float* __restrict__ posbuf) {
    const int ct = blockIdx.x;     // 0..499 col-tile
    const int rt = blockIdx.y;     // 0..3   row-tile
    const int C0 = ct * BN;
    const int R0 = rt * BM;
    const int tid  = threadIdx.x;
    const int lane = tid & 63;
    const int w    = tid >> 6;
    const int wm   = w >> 1;       // row half 0..1
    const int wn   = w & 1;        // col half 0..1
    const int lr   = lane & 15;
    const int lk   = lane >> 4;

    __shared__ ushort sA[BM][264];   // 67.6 KB, stride 33x16B -> conflict-free
    __shared__ ushort sB[BN][36];    // 9.2 KB per K-step
    __shared__ int    s_lab[BM];
    __shared__ int    s_cam[BM];
    __shared__ float  s_intra[BM];
    __shared__ float  s_wred[8];
    __shared__ float  s_tau;

    // ---- stage A-tile once: 128 rows x 256 k (bf16, L2-resident source) ----
#pragma unroll
    for (int it = 0; it < 16; ++it) {
        int q   = tid + it * 256;      // 16B-chunk id, 0..4095
        int row = q >> 5;              // 0..127
        int c16 = q & 31;              // 16B chunk within row
        *(bf16x8*)(&sA[row][c16 * 8]) =
            *(const bf16x8*)(A + (size_t)(R0 + row) * DDIM + c16 * 8);
    }
    if (tid < BM) {
        s_lab[tid] = labels[R0 + tid];
        s_cam[tid] = cams[R0 + tid];
        s_intra[tid] = 0.0f;
    }

    // ---- stage B K-step 0 ----
#pragma unroll
    for (int it = 0; it < 4; ++it) {
        int q   = tid + it * 256;      // f32x4 chunk, 0..1023
        int col = q >> 3;              // 0..127
        int k4  = q & 7;               // f32x4 within 32-k step
        f32x4 v = *(const f32x4*)(B + (size_t)(C0 + col) * DDIM + k4 * 4);
        ushort4 o = { f2bf(v[0]), f2bf(v[1]), f2bf(v[2]), f2bf(v[3]) };
        *(ushort4*)(&sB[col][k4 * 4]) = o;
    }
    __syncthreads();

    // ---- K-loop: 8 steps, both operands from LDS ----
    f32x4 zero = {0.f, 0.f, 0.f, 0.f};
    f32x4 acc[4][4];
#pragma unroll
    for (int m = 0; m < 4; ++m)
#pragma unroll
        for (int nn = 0; nn < 4; ++nn) acc[m][nn] = zero;

    for (int ks = 0; ks < 8; ++ks) {
        bf16x8 af[4], bf[4];
#pragma unroll
        for (int m = 0; m < 4; ++m)
            af[m] = *(const bf16x8*)(&sA[wm * 64 + m * 16 + lr][ks * 32 + lk * 8]);
#pragma unroll
        for (int nn = 0; nn < 4; ++nn)
            bf[nn] = *(const bf16x8*)(&sB[wn * 64 + nn * 16 + lr][lk * 8]);
#pragma unroll
        for (int m = 0; m < 4; ++m)
#pragma unroll
            for (int nn = 0; nn < 4; ++nn)
                acc[m][nn] = __builtin_amdgcn_mfma_f32_16x16x32_bf16(af[m], bf[nn], acc[m][nn], 0, 0, 0);
        if (ks < 7) {
            __syncthreads();           // drain frag reads before overwrite
#pragma unroll
            for (int it = 0; it < 4; ++it) {
                int q   = tid + it * 256;
                int col = q >> 3;
                int k4  = q & 7;
                f32x4 v = *(const f32x4*)(B + (size_t)(C0 + col) * DDIM + (ks + 1) * 32 + k4 * 4);
                ushort4 o = { f2bf(v[0]), f2bf(v[1]), f2bf(v[2]), f2bf(v[3]) };
                *(ushort4*)(&sB[col][k4 * 4]) = o;
            }
            __syncthreads();
        }
    }

    // ---- per-block sigma from own accumulators (clip |v|<0.25 = 4*sigma) ----
    float ss = 0.0f, sc2 = 0.0f;
#pragma unroll
    for (int m = 0; m < 4; ++m)
#pragma unroll
        for (int nn = 0; nn < 4; ++nn)
#pragma unroll
            for (int j = 0; j < 4; ++j) {
                float v = acc[m][nn][j];
                if (fabsf(v) < 0.25f) { ss += v * v; sc2 += 1.0f; }
            }
#pragma unroll
    for (int off = 32; off > 0; off >>= 1) {
        ss  += __shfl_down(ss, off);
        sc2 += __shfl_down(sc2, off);
    }
    if (lane == 0) { s_wred[w] = ss; s_wred[4 + w] = sc2; }
    __syncthreads();
    if (tid == 0) {
        float S = s_wred[0] + s_wred[1] + s_wred[2] + s_wred[3];
        float C = s_wred[4] + s_wred[5] + s_wred[6] + s_wred[7];
        s_tau = 2.9f * sqrtf(S / fmaxf(C, 1.0f));
    }
    __syncthreads();
    const float tau = s_tau;

    // ---- epilogue: C/D layout col = lane&15 (+16nn), row = lk*4+j (+16m) ----
#pragma unroll
    for (int m = 0; m < 4; ++m) {
#pragma unroll
        for (int j = 0; j < 4; ++j) {
            const int rl  = wm * 64 + m * 16 + lk * 4 + j;
            const int r   = R0 + rl;
            const int lab = s_lab[rl];
            const int cm  = s_cam[rl];
            const bool mycam = ((lr & 7) == cm);
            float isum = 0.0f;
#pragma unroll
            for (int nn = 0; nn < 4; ++nn) {
                const int c_loc = wn * 64 + nn * 16 + lr;
                const float v = acc[m][nn][j];
                if (mycam) isum += exp2f(v * K2C);
                const int g = (C0 + c_loc) >> 3;
                if (g == lab) {
                    posbuf[r * CC + (c_loc & 7)] = v;
                } else if (v > tau) {
                    int id = atomicAdd(&gcount[r], 1);
                    if (id < CAP) cand[(size_t)r * CAP + id] = v;
                }
            }
            if (mycam) atomicAdd(&s_intra[rl], isum);
        }
    }
    __syncthreads();
    if (tid < BM) partial[(size_t)ct * NS + R0 + tid] = s_intra[tid];
}

// ---------------------------------------------------------------------------
// Kernel 3: per-row losses, with merged fixup backstop (block-uniform path).
__global__ __launch_bounds__(256)
void k_row(const ushort* __restrict__ fb, const float* __restrict__ B,
           const float* __restrict__ partial, const float* __restrict__ cand,
           const int* __restrict__ gcount, const float* __restrict__ posbuf,
           const int* __restrict__ labels, const int* __restrict__ cams,
           float* __restrict__ li, float* __restrict__ le) {
    const int n = blockIdx.x;
    const int tid = threadIdx.x;
    __shared__ float red[256];
    __shared__ int   redi[256];
    __shared__ float spos[CC];
    __shared__ float scand[CAP];
    __shared__ float f[DDIM];
    __shared__ float s_lo, s_hi;
    __shared__ int   s_done, s_cnt;

    // ---- intra: sum NCT partials ----
    float s = 0.0f;
    for (int b = tid; b < NCT; b += 256) s += partial[(size_t)b * NS + n];
    red[tid] = s;
    __syncthreads();
    for (int off = 128; off > 0; off >>= 1) {
        if (tid < off) red[tid] += red[tid + off];
        __syncthreads();
    }
    if (tid < CC) spos[tid] = posbuf[n * CC + tid];
    __syncthreads();
    if (tid == 0) li[n] = logf(red[0]) - 20.0f * spos[cams[n]];

    // ---- candidates: fast path or bisection fixup (block-uniform) ----
    int c = gcount[n];
    if (c >= KTOP && c <= CAP) {
        for (int i = tid; i < c; i += 256) scand[i] = cand[(size_t)n * CAP + i];
    } else {
        if (tid < DDIM) f[tid] = bf2f(fb[(size_t)n * DDIM + tid]);
        const int label = labels[n];
        if (tid == 0) { s_lo = -1.01f; s_hi = 1.01f; s_done = 0; s_cnt = 0; }
        __syncthreads();
        for (int it = 0; it < 16; ++it) {
            if (s_done) break;                     // uniform: settled by barrier
            float tm = 0.5f * (s_lo + s_hi);
            int cnt = 0;
            for (int p = tid; p < PP; p += 256) {
                if ((p >> 3) == label) continue;
                const float* col = B + (size_t)p * DDIM;
                float d = 0.0f;
                for (int k = 0; k < DDIM; ++k) d += f[k] * bf2f(f2bf(col[k]));
                cnt += (d > tm);
            }
            redi[tid] = cnt;
            __syncthreads();
            for (int off = 128; off > 0; off >>= 1) {
                if (tid < off) redi[tid] += redi[tid + off];
                __syncthreads();
            }
            int tot = redi[0];
            __syncthreads();
            if (tot >= KTOP && tot <= CAP) {
                if (tid == 0) s_cnt = 0;
                __syncthreads();
                for (int p = tid; p < PP; p += 256) {
                    if ((p >> 3) == label) continue;
                    const float* col = B + (size_t)p * DDIM;
                    float d = 0.0f;
                    for (int k = 0; k < DDIM; ++k) d += f[k] * bf2f(f2bf(col[k]));
                    if (d > tm) {
                        int id = atomicAdd(&s_cnt, 1);
                        if (id < CAP) scand[id] = d;
                    }
                }
                __syncthreads();
                if (tid == 0) s_done = 1;
            } else {
                if (tid == 0) { if (tot < KTOP) s_hi = tm; else s_lo = tm; }
            }
            __syncthreads();
        }
        if (!s_done) {   // last resort: collect at s_lo, truncate at CAP
            if (tid == 0) s_cnt = 0;
            __syncthreads();
            float tl = s_lo;
            for (int p = tid; p < PP; p += 256) {
                if ((p >> 3) == label) continue;
                const float* col = B + (size_t)p * DDIM;
                float d = 0.0f;
                for (int k = 0; k < DDIM; ++k) d += f[k] * bf2f(f2bf(col[k]));
                if (d > tl) {
                    int id = atomicAdd(&s_cnt, 1);
                    if (id < CAP) scand[id] = d;
                }
            }
        }
        __syncthreads();
        c = s_cnt;
        if (c > CAP) c = CAP;
    }
    __syncthreads();

    // ---- inter: exact top-K by rank counting + positives ----
    float sum = 0.0f;
    for (int i = tid; i < c; i += 256) {
        float v = scand[i];
        int rk = 0;
        for (int j = 0; j < c; ++j) {
            float u = scand[j];
            rk += (u > v) || (u == v && j < i);
        }
        if (rk < KTOP) sum += exp2f(v * K2C);
    }
    if (tid < CC) sum += exp2f(spos[tid] * K2C);
    red[tid] = sum;
    __syncthreads();
    for (int off = 128; off > 0; off >>= 1) {
        if (tid < off) red[tid] += red[tid + off];
        __syncthreads();
    }
    if (tid == 0) {
        float ps = 0.0f;
#pragma unroll
        for (int j = 0; j < CC; ++j) ps += spos[j];
        le[n] = logf(red[0]) - 2.5f * ps;   // 20/8 = 2.5
    }
}

// ---------------------------------------------------------------------------
// Kernel 4: per-camera segment means -> 2 outputs.
__global__ void k_finalize(const float* __restrict__ li, const float* __restrict__ le,
                           const int* __restrict__ cams, float* __restrict__ out) {
    __shared__ float si[CC], se[CC];
    __shared__ int sc[CC];
    int tid = threadIdx.x;
    if (tid < CC) { si[tid] = 0.f; se[tid] = 0.f; sc[tid] = 0; }
    __syncthreads();
    for (int i = tid; i < NS; i += 256) {
        int cm = cams[i];
        atomicAdd(&si[cm], li[i]);
        atomicAdd(&se[cm], le[i]);
        atomicAdd(&sc[cm], 1);
    }
    __syncthreads();
    if (tid == 0) {
        float a = 0.f, b = 0.f;
        for (int cm = 0; cm < CC; ++cm) {
            if (sc[cm] > 0) {
                a += si[cm] / (float)sc[cm];
                b += se[cm] / (float)sc[cm];
            }
        }
        out[0] = a;
        out[1] = 0.5f * b;
    }
}

// ---------------------------------------------------------------------------
extern "C" void kernel_launch(void* const* d_in, const int* in_sizes, int n_in,
                              void* d_out, int out_size, void* d_ws, size_t ws_size,
                              hipStream_t stream) {
    const float* feats   = (const float*)d_in[0];
    const int*   indexes = (const int*)d_in[1];
    const int*   ltab    = (const int*)d_in[2];
    const int*   ctab    = (const int*)d_in[3];
    const float* centers = (const float*)d_in[4];
    float* out = (float*)d_out;

    char* p = (char*)d_ws;
    float*  cand    = (float*)p;   p += (size_t)NS * CAP * sizeof(float);   // 2.10 MB
    float*  partial = (float*)p;   p += (size_t)NCT * NS * sizeof(float);   // 1.02 MB
    float*  posbuf  = (float*)p;   p += (size_t)NS * CC * sizeof(float);    // 16 KB
    ushort* fb      = (ushort*)p;  p += (size_t)NS * DDIM * sizeof(ushort); // 256 KB
    int*    labels  = (int*)p;     p += 2048;
    int*    cams    = (int*)p;     p += 2048;
    float*  li      = (float*)p;   p += 2048;
    float*  le      = (float*)p;   p += 2048;
    int*    gcount  = (int*)p;     p += 2048;

    hipLaunchKernelGGL(k_norm_gather, dim3(NS), dim3(64), 0, stream,
                       feats, indexes, ltab, ctab, fb, labels, cams, gcount);
    hipLaunchKernelGGL(k_gemm_fused, dim3(NCT, 4), dim3(256), 0, stream,
                       fb, centers, labels, cams, partial, cand, gcount, posbuf);
    hipLaunchKernelGGL(k_row, dim3(NS), dim3(256), 0, stream,
                       fb, centers, partial, cand, gcount, posbuf, labels, cams, li, le);
    hipLaunchKernelGGL(k_finalize, dim3(1), dim3(256), 0, stream, li, le, cams, out);
}